// Round 10
// baseline (618.880 us; speedup 1.0000x reference)
//
#include <hip/hip_runtime.h>
#include <hip/hip_bf16.h>

#define B 1024
#define H 1024
#define T 512
#define NUM 44
#define IN 128
#define AK (IN + 2 * H)   // 2176
#define XC (IN + H)       // 1152
#define G4 (4 * H)        // 4096
#define BH ((size_t)B * H)

typedef __attribute__((ext_vector_type(8))) short s16x8;
typedef __attribute__((ext_vector_type(4))) float f32x4;

__device__ __forceinline__ unsigned short f2bf(float f) {
    unsigned u = __float_as_uint(f);
    unsigned r = (u + 0x7fffu + ((u >> 16) & 1u)) >> 16;
    return (unsigned short)r;
}
__device__ __forceinline__ float bf2f(unsigned short u) {
    return __uint_as_float(((unsigned)u) << 16);
}
__device__ __forceinline__ float sigmf(float v) { return 1.0f / (1.0f + expf(-v)); }

__device__ __forceinline__ void gload16(const ushort* g, ushort* l) {
    __builtin_amdgcn_global_load_lds(
        (const __attribute__((address_space(1))) void*)g,
        (__attribute__((address_space(3))) void*)l,
        16, 0, 0);
}

#define TM 128
#define TN 128
#define TK 32

// ---------------- 128x128 GEMM core: C = X@W^T -> f32 and/or bf16 out ----------------
__device__ __forceinline__ void gemm_core(
    const ushort* __restrict__ X, const ushort* __restrict__ W,
    float* __restrict__ Cf, ushort* __restrict__ Cb,
    int kbeg, int kend, int ldx, int ldw, int ldc,
    int m0, int n0, ushort (*As)[TK], ushort (*Bs)[TK])
{
    const int tid = threadIdx.x;
    const int lane = tid & 63;
    const int wid = tid >> 6;
    const int wm = wid >> 1, wn = wid & 1;
    const int srow = wid * 32 + (lane >> 2);
    const int skc  = (lane & 3) * 8;

    f32x4 acc[4][4] = {};

    for (int k0 = kbeg; k0 < kend; k0 += TK) {
        gload16(X + (size_t)(m0 + srow) * ldx + k0 + skc,      &As[wid * 32][0]);
        gload16(X + (size_t)(m0 + srow + 16) * ldx + k0 + skc, &As[wid * 32 + 16][0]);
        gload16(W + (size_t)(n0 + srow) * ldw + k0 + skc,      &Bs[wid * 32][0]);
        gload16(W + (size_t)(n0 + srow + 16) * ldw + k0 + skc, &Bs[wid * 32 + 16][0]);
        __syncthreads();

        s16x8 a[4], b[4];
        #pragma unroll
        for (int m = 0; m < 4; ++m)
            a[m] = *(const s16x8*)&As[wm * 64 + m * 16 + (lane & 15)][(lane >> 4) * 8];
        #pragma unroll
        for (int n = 0; n < 4; ++n)
            b[n] = *(const s16x8*)&Bs[wn * 64 + n * 16 + (lane & 15)][(lane >> 4) * 8];
        #pragma unroll
        for (int m = 0; m < 4; ++m)
            #pragma unroll
            for (int n = 0; n < 4; ++n)
                acc[m][n] = __builtin_amdgcn_mfma_f32_16x16x32_bf16(a[m], b[n], acc[m][n], 0, 0, 0);
        __syncthreads();
    }

    #pragma unroll
    for (int m = 0; m < 4; ++m) {
        #pragma unroll
        for (int n = 0; n < 4; ++n) {
            int col = n0 + wn * 64 + n * 16 + (lane & 15);
            #pragma unroll
            for (int j = 0; j < 4; ++j) {
                int row = m0 + wm * 64 + m * 16 + (lane >> 4) * 4 + j;
                float v = acc[m][n][j];
                if (Cf) Cf[(size_t)row * ldc + col] = v;
                if (Cb) Cb[(size_t)row * ldc + col] = f2bf(v);
            }
        }
    }
}

// ---------------- ALL parallel GEMMs: logits splitK (128) + hh x2 (512) + W_f (288) ----------------
// whh/wih0 are gate-interleaved-row buffers -> hh partials & W_f come out gate-interleaved.
__global__ __launch_bounds__(256) void allgemms_kernel(
    const ushort* __restrict__ attn_in, const ushort* __restrict__ attn_w_bf,
    float* __restrict__ logits_p,
    const ushort* __restrict__ h0_bf,
    const ushort* __restrict__ whh0p, const ushort* __restrict__ whh1p,
    ushort* __restrict__ g1part, ushort* __restrict__ g2part,
    const ushort* __restrict__ wih0p, const ushort* __restrict__ comb_wT_bf,
    ushort* __restrict__ W_f_bf)
{
    __shared__ ushort As[TM][TK];
    __shared__ ushort Bs[TN][TK];
    const int rid = blockIdx.x;
    if (rid < 128) {
        int z = rid >> 5, t = rid & 31;
        int m0 = (t >> 2) * TM, n0 = (t & 3) * TN;
        gemm_core(attn_in, attn_w_bf, logits_p + (size_t)z * B * T, nullptr,
                  z * 544, z * 544 + 544, AK, AK, T, m0, n0, As, Bs);
    } else if (rid < 640) {
        int layer = (rid - 128) >> 8;
        int t = (rid - 128) & 255;
        int m0 = (t >> 5) * TM, n0 = (t & 31) * TN;
        gemm_core(h0_bf + (size_t)layer * BH, layer ? whh1p : whh0p,
                  nullptr, layer ? g2part : g1part,
                  0, H, H, H, G4, m0, n0, As, Bs);
    } else {
        int t = rid - 640;
        int m0 = (t / 9) * TM, n0 = (t % 9) * TN;
        gemm_core(wih0p, comb_wT_bf, nullptr, W_f_bf,
                  0, IN, IN, IN, XC, m0, n0, As, Bs);
    }
}

// ---------------- TM=64 x TN=128 GEMM + fused LSTM epilogue (quad-shfl gate exchange) ----------------
// W rows gate-interleaved (row 4u+g), biasp/CinBf in same col order. col&3 == lane&3 == gate.
__global__ __launch_bounds__(256) void gemm64_lstm_kernel(
    const ushort* __restrict__ X, const ushort* __restrict__ W,
    const float* __restrict__ biasp, const ushort* __restrict__ CinBf,
    const float* __restrict__ c_in, float* __restrict__ h_out, float* __restrict__ c_out,
    ushort* __restrict__ h_bf, int K)
{
    __shared__ ushort As[64][TK];
    __shared__ ushort Bs[128][TK];
    const int tid = threadIdx.x;
    const int lane = tid & 63;
    const int wid = tid >> 6;
    const int wm = wid >> 1, wn = wid & 1;
    const int m0 = blockIdx.y * 64;     // batch rows
    const int n0 = blockIdx.x * 128;    // gate cols (interleaved)
    const int skc = (lane & 3) * 8;

    f32x4 acc[2][4] = {};

    for (int k0 = 0; k0 < K; k0 += TK) {
        gload16(X + (size_t)(m0 + wid * 16 + (lane >> 2)) * K + k0 + skc, &As[wid * 16][0]);
        gload16(W + (size_t)(n0 + wid * 32 + (lane >> 2)) * K + k0 + skc, &Bs[wid * 32][0]);
        gload16(W + (size_t)(n0 + wid * 32 + 16 + (lane >> 2)) * K + k0 + skc, &Bs[wid * 32 + 16][0]);
        __syncthreads();
        s16x8 a[2], b[4];
        #pragma unroll
        for (int m = 0; m < 2; ++m)
            a[m] = *(const s16x8*)&As[wm * 32 + m * 16 + (lane & 15)][(lane >> 4) * 8];
        #pragma unroll
        for (int n = 0; n < 4; ++n)
            b[n] = *(const s16x8*)&Bs[wn * 64 + n * 16 + (lane & 15)][(lane >> 4) * 8];
        #pragma unroll
        for (int m = 0; m < 2; ++m)
            #pragma unroll
            for (int n = 0; n < 4; ++n)
                acc[m][n] = __builtin_amdgcn_mfma_f32_16x16x32_bf16(a[m], b[n], acc[m][n], 0, 0, 0);
        __syncthreads();
    }

    const int q = lane & 3;
    #pragma unroll
    for (int m = 0; m < 2; ++m) {
        #pragma unroll
        for (int n = 0; n < 4; ++n) {
            int col = n0 + wn * 64 + n * 16 + (lane & 15);
            int u = col >> 2;                 // unit index (same across the quad)
            float badd = biasp[col];
            #pragma unroll
            for (int j = 0; j < 4; ++j) {
                int row = m0 + wm * 32 + m * 16 + (lane >> 4) * 4 + j;
                float pre = acc[m][n][j] + badd + bf2f(CinBf[(size_t)row * G4 + col]);
                float f1 = __shfl_xor(pre, 1, 64);
                float f2 = __shfl_xor(pre, 2, 64);
                float f3 = __shfl_xor(pre, 3, 64);
                float gi = q == 0 ? pre : q == 1 ? f1 : q == 2 ? f2 : f3;
                float gf = q == 0 ? f1 : q == 1 ? pre : q == 2 ? f3 : f2;
                float gg = q == 0 ? f2 : q == 1 ? f3 : q == 2 ? pre : f1;
                float go = q == 0 ? f3 : q == 1 ? f2 : q == 2 ? f1 : pre;
                float cprev = c_in[(size_t)row * H + u];
                float c = sigmf(gf) * cprev + sigmf(gi) * tanhf(gg);
                float h = sigmf(go) * tanhf(c);
                if (q == 0) {
                    h_out[(size_t)row * H + u] = h;
                    c_out[(size_t)row * H + u] = c;
                    if (h_bf) h_bf[(size_t)row * H + u] = f2bf(h);
                }
            }
        }
    }
}

// ---------------- preamble: converts (plain + gate-perm) + transpose + biases + build ----------------
#define P0 2048            // h0 plain (f4)
#define P1 (P0 + 1088)     // attn_w plain
#define P2 (P1 + 512)      // w_ih0 gate-perm (32 f4/row)
#define P3 (P2 + 4096)     // w_hh0 gate-perm (256 f4/row)
#define P4 (P3 + 4096)     // w_ih1 gate-perm
#define P5 (P4 + 4096)     // w_hh1 gate-perm
#define P6 (P5 + 576)      // comb_w transpose
#define P7 (P6 + 16)       // bias_f (perm)
#define P8 (P7 + 16)       // bias2p (perm)
#define P9 (P8 + 1024)     // build attn_in

__global__ __launch_bounds__(256) void preamble_kernel(
    const float* __restrict__ h0, const float* __restrict__ attn_w,
    const float* __restrict__ w_ih0, const float* __restrict__ w_hh0,
    const float* __restrict__ w_ih1, const float* __restrict__ w_hh1,
    const float* __restrict__ comb_w, const float* __restrict__ comb_b,
    const float* __restrict__ b_ih0, const float* __restrict__ b_hh0,
    const float* __restrict__ b_ih1, const float* __restrict__ b_hh1,
    const float* __restrict__ x, const int* __restrict__ x_emb,
    const float* __restrict__ c0,
    const float* __restrict__ e0, const float* __restrict__ e1,
    const float* __restrict__ e2, const float* __restrict__ e3,
    ushort* __restrict__ h0_bf, ushort* __restrict__ attn_w_bf,
    ushort* __restrict__ wih0p, ushort* __restrict__ whh0p,
    ushort* __restrict__ wih1p, ushort* __restrict__ whh1p,
    ushort* __restrict__ comb_wT, float* __restrict__ biasf, float* __restrict__ bias2p,
    ushort* __restrict__ attn_in, ushort* __restrict__ xctx)
{
    const int bid = blockIdx.x;
    const int tid = threadIdx.x;

    if (bid < P1) {   // plain converts
        const float* s; ushort* d; int f;
        if (bid < P0) { f = bid * 256 + tid;        s = h0;     d = h0_bf; }
        else          { f = (bid - P0) * 256 + tid; s = attn_w; d = attn_w_bf; }
        float4 v = ((const float4*)s)[f];
        ushort4 o = {f2bf(v.x), f2bf(v.y), f2bf(v.z), f2bf(v.w)};
        ((ushort4*)d)[f] = o;
    } else if (bid < P2) {   // wih0 gate-perm (row = 32 f4)
        int f = (bid - P1) * 256 + tid;
        int r = f >> 5, c = f & 31;
        int srcrow = ((r & 3) << 10) + (r >> 2);
        float4 v = ((const float4*)w_ih0)[srcrow * 32 + c];
        ushort4 o = {f2bf(v.x), f2bf(v.y), f2bf(v.z), f2bf(v.w)};
        ((ushort4*)wih0p)[f] = o;
    } else if (bid < P5) {   // whh0/wih1/whh1 gate-perm (row = 256 f4)
        const float* s; ushort* d; int f;
        if (bid < P3)      { f = (bid - P2) * 256 + tid; s = w_hh0; d = whh0p; }
        else if (bid < P4) { f = (bid - P3) * 256 + tid; s = w_ih1; d = wih1p; }
        else               { f = (bid - P4) * 256 + tid; s = w_hh1; d = whh1p; }
        int r = f >> 8, c = f & 255;
        int srcrow = ((r & 3) << 10) + (r >> 2);
        float4 v = ((const float4*)s)[srcrow * 256 + c];
        ushort4 o = {f2bf(v.x), f2bf(v.y), f2bf(v.z), f2bf(v.w)};
        ((ushort4*)d)[f] = o;
    } else if (bid < P6) {
        int e = (bid - P5) * 256 + tid;
        int j = e >> 7, k = e & 127;
        comb_wT[e] = f2bf(comb_w[(size_t)k * XC + j]);
    } else if (bid < P7) {
        __shared__ float cb[IN];
        for (int i = tid; i < IN; i += 256) cb[i] = comb_b[i];
        __syncthreads();
        int p = (bid - P6) * 256 + tid;
        int srow = ((p & 3) << 10) + (p >> 2);
        float s = b_ih0[srow] + b_hh0[srow];
        const float* row = w_ih0 + (size_t)srow * IN;
        #pragma unroll 8
        for (int j = 0; j < IN; ++j) s += row[j] * cb[j];
        biasf[p] = s;
    } else if (bid < P8) {
        int p = (bid - P7) * 256 + tid;
        int srow = ((p & 3) << 10) + (p >> 2);
        bias2p[p] = b_ih1[srow] + b_hh1[srow];
    } else {
        int b = bid - P8;
        int id0 = x_emb[b * 4 + 0];
        int id1 = x_emb[b * 4 + 1];
        int id2 = x_emb[b * 4 + 2];
        int id3 = x_emb[b * 4 + 3];
        ushort* dst = attn_in + (size_t)b * AK;
        for (int j = tid; j < AK; j += 256) {
            float v;
            if (j < 44)        v = x[b * NUM + j];
            else if (j < 108)  v = e0[id0 * 64 + (j - 44)];
            else if (j < 116)  v = e1[id1 * 8 + (j - 108)];
            else if (j < 124)  v = e2[id2 * 8 + (j - 116)];
            else if (j < 128)  v = e3[id3 * 4 + (j - 124)];
            else if (j < 1152) v = h0[b * H + (j - 128)];
            else               v = c0[b * H + (j - 1152)];
            unsigned short bf = f2bf(v);
            dst[j] = bf;
            if (j < IN) xctx[(size_t)b * XC + j] = bf;
        }
    }
}

// ---------------- softmax (merges split-K logits) -> aw_out ----------------
__global__ __launch_bounds__(256) void softmax_kernel(
    const float* __restrict__ logits_p, const float* __restrict__ attn_b,
    float* __restrict__ aw)
{
    int b = blockIdx.x;
    int tid = threadIdx.x;
    __shared__ float red[8];
    float v0 = attn_b[tid], v1 = attn_b[tid + 256];
    #pragma unroll
    for (int z = 0; z < 4; ++z) {
        const float* lp = logits_p + (size_t)z * B * T + (size_t)b * T;
        v0 += lp[tid];
        v1 += lp[tid + 256];
    }
    float m = fmaxf(v0, v1);
    #pragma unroll
    for (int off = 32; off > 0; off >>= 1) m = fmaxf(m, __shfl_down(m, off, 64));
    if ((tid & 63) == 0) red[tid >> 6] = m;
    __syncthreads();
    m = fmaxf(fmaxf(red[0], red[1]), fmaxf(red[2], red[3]));
    float e0 = expf(v0 - m), e1 = expf(v1 - m);
    float s = e0 + e1;
    #pragma unroll
    for (int off = 32; off > 0; off >>= 1) s += __shfl_down(s, off, 64);
    if ((tid & 63) == 0) red[4 + (tid >> 6)] = s;
    __syncthreads();
    s = red[4] + red[5] + red[6] + red[7];
    float inv = 1.0f / s;
    aw[(size_t)b * T + tid]       = e0 * inv;
    aw[(size_t)b * T + tid + 256] = e1 * inv;
}

// ---------------- ctx stream: t-split x2, lean ----------------
__global__ __launch_bounds__(256) void ctx_kernel(
    const float* __restrict__ enc, const float* __restrict__ aw,
    float* __restrict__ ctxp)
{
    const int b = blockIdx.x >> 1;
    const int z = blockIdx.x & 1;
    const int tid = threadIdx.x;
    __shared__ float w[256];
    w[tid] = aw[(size_t)b * T + z * 256 + tid];
    __syncthreads();

    const float* p = enc + (size_t)(z * 256) * BH + (size_t)b * H + tid * 4;
    float4 acc = {0.f, 0.f, 0.f, 0.f};
    for (int t0 = 0; t0 < 256; t0 += 8) {
        float4 vv[8];
        #pragma unroll
        for (int u = 0; u < 8; ++u)
            vv[u] = *(const float4*)(p + (size_t)(t0 + u) * BH);
        #pragma unroll
        for (int u = 0; u < 8; ++u) {
            float sw = w[t0 + u];
            acc.x += sw * vv[u].x; acc.y += sw * vv[u].y;
            acc.z += sw * vv[u].z; acc.w += sw * vv[u].w;
        }
    }
    *(float4*)(ctxp + (size_t)z * BH + (size_t)b * H + tid * 4) = acc;
}

// ---------------- ctx partial reduce (x2) -> xctx bf16 ----------------
__global__ __launch_bounds__(256) void ctx_reduce_kernel(
    const float* __restrict__ ctxp, ushort* __restrict__ xctx)
{
    int i = blockIdx.x * 256 + threadIdx.x;
    float4 a = ((const float4*)ctxp)[i];
    float4 c = ((const float4*)(ctxp + BH))[i];
    int f = i * 4;
    int b = f >> 10, h = f & 1023;
    ushort4 o = {f2bf(a.x + c.x), f2bf(a.y + c.y), f2bf(a.z + c.z), f2bf(a.w + c.w)};
    *(ushort4*)(xctx + (size_t)b * XC + IN + h) = o;
}

// ---------------- pred ----------------
__global__ __launch_bounds__(256) void pred_kernel(
    const float* __restrict__ h2, const float* __restrict__ pw,
    const float* __restrict__ pb, float* __restrict__ out)
{
    int b = blockIdx.x;
    const float* row = h2 + (size_t)b * H;
    float s = 0.f;
    for (int j = threadIdx.x; j < H; j += 256) s += row[j] * pw[j];
    #pragma unroll
    for (int off = 32; off > 0; off >>= 1) s += __shfl_down(s, off, 64);
    __shared__ float sm[4];
    if ((threadIdx.x & 63) == 0) sm[threadIdx.x >> 6] = s;
    __syncthreads();
    if (threadIdx.x == 0) out[b] = sm[0] + sm[1] + sm[2] + sm[3] + pb[0];
}

extern "C" void kernel_launch(void* const* d_in, const int* in_sizes, int n_in,
                              void* d_out, int out_size, void* d_ws, size_t ws_size,
                              hipStream_t stream) {
    (void)in_sizes; (void)n_in; (void)out_size; (void)ws_size;
    const float* x      = (const float*)d_in[0];
    const int*   x_emb  = (const int*)d_in[1];
    const float* h0     = (const float*)d_in[2];
    const float* c0     = (const float*)d_in[3];
    const float* enc    = (const float*)d_in[4];
    const float* emb0   = (const float*)d_in[5];
    const float* emb1   = (const float*)d_in[6];
    const float* emb2   = (const float*)d_in[7];
    const float* emb3   = (const float*)d_in[8];
    const float* attn_w = (const float*)d_in[9];
    const float* attn_b = (const float*)d_in[10];
    const float* comb_w = (const float*)d_in[11];
    const float* comb_b = (const float*)d_in[12];
    const float* w_ih0  = (const float*)d_in[13];
    const float* w_hh0  = (const float*)d_in[14];
    const float* b_ih0  = (const float*)d_in[15];
    const float* b_hh0  = (const float*)d_in[16];
    const float* w_ih1  = (const float*)d_in[17];
    const float* w_hh1  = (const float*)d_in[18];
    const float* b_ih1  = (const float*)d_in[19];
    const float* b_hh1  = (const float*)d_in[20];
    const float* pred_w = (const float*)d_in[21];
    const float* pred_b = (const float*)d_in[22];

    float* out = (float*)d_out;
    float* h1_out = out + 1024;
    float* h2_out = out + 1024 + BH;
    float* c1_out = out + 1024 + 2 * BH;
    float* c2_out = out + 1024 + 3 * BH;
    float* aw_out = out + 1024 + 4 * BH;

    char* w = (char*)d_ws;
    ushort* attn_in_bf = (ushort*)w;  w += (size_t)B * AK * 2;
    ushort* h0_bf      = (ushort*)w;  w += (size_t)2 * BH * 2;
    ushort* attn_w_bf  = (ushort*)w;  w += (size_t)T * AK * 2;
    ushort* wih0p      = (ushort*)w;  w += (size_t)G4 * IN * 2;
    ushort* whh0p      = (ushort*)w;  w += (size_t)G4 * H * 2;
    ushort* wih1p      = (ushort*)w;  w += (size_t)G4 * H * 2;
    ushort* whh1p      = (ushort*)w;  w += (size_t)G4 * H * 2;
    ushort* comb_wT_bf = (ushort*)w;  w += (size_t)XC * IN * 2;
    ushort* W_f_bf     = (ushort*)w;  w += (size_t)G4 * XC * 2;   // gate-interleaved rows
    float*  bias_f     = (float*)w;   w += (size_t)G4 * 4;        // perm
    float*  bias2p     = (float*)w;   w += (size_t)G4 * 4;        // perm
    ushort* xctx_bf    = (ushort*)w;  w += (size_t)B * XC * 2;
    ushort* h1_bf      = (ushort*)w;  w += (size_t)BH * 2;
    ushort* g1part     = (ushort*)w;  w += (size_t)B * G4 * 2;    // bf16 hh gates (perm cols)
    ushort* g2part     = (ushort*)w;  w += (size_t)B * G4 * 2;
    float*  logits_p   = (float*)w;   w += (size_t)4 * B * T * 4;
    float*  ctxp       = (float*)w;   w += (size_t)2 * BH * 4;
    // total ~70 MB

    preamble_kernel<<<P9, 256, 0, stream>>>(
        h0, attn_w, w_ih0, w_hh0, w_ih1, w_hh1, comb_w, comb_b,
        b_ih0, b_hh0, b_ih1, b_hh1,
        x, x_emb, c0, emb0, emb1, emb2, emb3,
        h0_bf, attn_w_bf, wih0p, whh0p, wih1p, whh1p, comb_wT_bf,
        bias_f, bias2p, attn_in_bf, xctx_bf);

    // logits splitK + hh0 + hh1 + W_f : one launch, 928 blocks
    allgemms_kernel<<<928, 256, 0, stream>>>(
        attn_in_bf, attn_w_bf, logits_p,
        h0_bf, whh0p, whh1p, g1part, g2part,
        wih0p, comb_wT_bf, W_f_bf);

    softmax_kernel<<<B, 256, 0, stream>>>(logits_p, attn_b, aw_out);

    // enc stream, t-split x2
    ctx_kernel<<<2048, 256, 0, stream>>>(enc, aw_out, ctxp);

    ctx_reduce_kernel<<<(int)(BH / 4 / 256), 256, 0, stream>>>(ctxp, xctx_bf);

    // layer 0: gates = xctx@W_f^T + g1part + bias_f -> LSTM -> h1,c1,h1_bf   (K=1152)
    gemm64_lstm_kernel<<<dim3(G4 / 128, B / 64), 256, 0, stream>>>(
        xctx_bf, W_f_bf, bias_f, g1part, c0, h1_out, c1_out, h1_bf, XC);

    // layer 1: gates = h1@wih1p^T + g2part + bias2p -> LSTM -> h2,c2   (K=1024)
    gemm64_lstm_kernel<<<dim3(G4 / 128, B / 64), 256, 0, stream>>>(
        h1_bf, wih1p, bias2p, g2part, c0 + BH, h2_out, c2_out, nullptr, H);

    pred_kernel<<<B, 256, 0, stream>>>(h2_out, pred_w, pred_b, out);
}

// Round 11
// 584.508 us; speedup vs baseline: 1.0588x; 1.0588x over previous
//
#include <hip/hip_runtime.h>
#include <hip/hip_bf16.h>

#define B 1024
#define H 1024
#define T 512
#define NUM 44
#define IN 128
#define AK (IN + 2 * H)   // 2176
#define XC (IN + H)       // 1152
#define G4 (4 * H)        // 4096
#define BH ((size_t)B * H)

typedef __attribute__((ext_vector_type(8))) short s16x8;
typedef __attribute__((ext_vector_type(4))) float f32x4;

__device__ __forceinline__ unsigned short f2bf(float f) {
    unsigned u = __float_as_uint(f);
    unsigned r = (u + 0x7fffu + ((u >> 16) & 1u)) >> 16;
    return (unsigned short)r;
}
__device__ __forceinline__ float bf2f(unsigned short u) {
    return __uint_as_float(((unsigned)u) << 16);
}
__device__ __forceinline__ float sigmf(float v) { return 1.0f / (1.0f + expf(-v)); }

__device__ __forceinline__ void gload16(const ushort* g, ushort* l) {
    __builtin_amdgcn_global_load_lds(
        (const __attribute__((address_space(1))) void*)g,
        (__attribute__((address_space(3))) void*)l,
        16, 0, 0);
}

#define TM 128
#define TN 128
#define TK 32

// ---------------- 128x128 GEMM core: C = X@W^T -> f32 and/or bf16 out ----------------
__device__ __forceinline__ void gemm_core(
    const ushort* __restrict__ X, const ushort* __restrict__ W,
    float* __restrict__ Cf, ushort* __restrict__ Cb,
    int kbeg, int kend, int ldx, int ldw, int ldc,
    int m0, int n0, ushort (*As)[TK], ushort (*Bs)[TK])
{
    const int tid = threadIdx.x;
    const int lane = tid & 63;
    const int wid = tid >> 6;
    const int wm = wid >> 1, wn = wid & 1;
    const int srow = wid * 32 + (lane >> 2);
    const int skc  = (lane & 3) * 8;

    f32x4 acc[4][4] = {};

    for (int k0 = kbeg; k0 < kend; k0 += TK) {
        gload16(X + (size_t)(m0 + srow) * ldx + k0 + skc,      &As[wid * 32][0]);
        gload16(X + (size_t)(m0 + srow + 16) * ldx + k0 + skc, &As[wid * 32 + 16][0]);
        gload16(W + (size_t)(n0 + srow) * ldw + k0 + skc,      &Bs[wid * 32][0]);
        gload16(W + (size_t)(n0 + srow + 16) * ldw + k0 + skc, &Bs[wid * 32 + 16][0]);
        __syncthreads();

        s16x8 a[4], b[4];
        #pragma unroll
        for (int m = 0; m < 4; ++m)
            a[m] = *(const s16x8*)&As[wm * 64 + m * 16 + (lane & 15)][(lane >> 4) * 8];
        #pragma unroll
        for (int n = 0; n < 4; ++n)
            b[n] = *(const s16x8*)&Bs[wn * 64 + n * 16 + (lane & 15)][(lane >> 4) * 8];
        #pragma unroll
        for (int m = 0; m < 4; ++m)
            #pragma unroll
            for (int n = 0; n < 4; ++n)
                acc[m][n] = __builtin_amdgcn_mfma_f32_16x16x32_bf16(a[m], b[n], acc[m][n], 0, 0, 0);
        __syncthreads();
    }

    #pragma unroll
    for (int m = 0; m < 4; ++m) {
        #pragma unroll
        for (int n = 0; n < 4; ++n) {
            int col = n0 + wn * 64 + n * 16 + (lane & 15);
            #pragma unroll
            for (int j = 0; j < 4; ++j) {
                int row = m0 + wm * 64 + m * 16 + (lane >> 4) * 4 + j;
                float v = acc[m][n][j];
                if (Cf) Cf[(size_t)row * ldc + col] = v;
                if (Cb) Cb[(size_t)row * ldc + col] = f2bf(v);
            }
        }
    }
}

// ---------------- ALL parallel GEMMs: logits splitK (128) + hh x2 (512) + W_f (288) ----------------
__global__ __launch_bounds__(256) void allgemms_kernel(
    const ushort* __restrict__ attn_in, const ushort* __restrict__ attn_w_bf,
    float* __restrict__ logits_p,
    const ushort* __restrict__ h0_bf,
    const ushort* __restrict__ whh0_bf, const ushort* __restrict__ whh1_bf,
    ushort* __restrict__ g1part, ushort* __restrict__ g2part,
    const ushort* __restrict__ wih0_bf, const ushort* __restrict__ comb_wT_bf,
    ushort* __restrict__ W_f_bf)
{
    __shared__ ushort As[TM][TK];
    __shared__ ushort Bs[TN][TK];
    const int rid = blockIdx.x;
    if (rid < 128) {
        int z = rid >> 5, t = rid & 31;
        int m0 = (t >> 2) * TM, n0 = (t & 3) * TN;
        gemm_core(attn_in, attn_w_bf, logits_p + (size_t)z * B * T, nullptr,
                  z * 544, z * 544 + 544, AK, AK, T, m0, n0, As, Bs);
    } else if (rid < 640) {
        // g_hh = h0[layer] @ w_hh^T -> bf16 [B][G4]
        int layer = (rid - 128) >> 8;
        int t = (rid - 128) & 255;
        int m0 = (t >> 5) * TM, n0 = (t & 31) * TN;
        gemm_core(h0_bf + (size_t)layer * BH, layer ? whh1_bf : whh0_bf,
                  nullptr, layer ? g2part : g1part,
                  0, H, H, H, G4, m0, n0, As, Bs);
    } else {
        // W_f = w_ih0 @ comb_w  (4096 x 1152, K=128) -> bf16
        int t = rid - 640;
        int m0 = (t / 9) * TM, n0 = (t % 9) * TN;
        gemm_core(wih0_bf, comb_wT_bf, nullptr, W_f_bf,
                  0, IN, IN, IN, XC, m0, n0, As, Bs);
    }
}

// ---------------- fat 128x128 tail GEMM: gates = X@W^T + bias(+bias2) + CinBf -> bf16 ----------------
__global__ __launch_bounds__(256) void gemm128_gates_kernel(
    const ushort* __restrict__ X, const ushort* __restrict__ W,
    const float* __restrict__ bias1, const float* __restrict__ bias2,
    const ushort* __restrict__ CinBf, ushort* __restrict__ Cb, int K)
{
    __shared__ ushort As[TM][TK];
    __shared__ ushort Bs[TN][TK];
    const int tid = threadIdx.x;
    const int lane = tid & 63;
    const int wid = tid >> 6;
    const int wm = wid >> 1, wn = wid & 1;
    const int m0 = blockIdx.y * TM;
    const int n0 = blockIdx.x * TN;
    const int srow = wid * 32 + (lane >> 2);
    const int skc  = (lane & 3) * 8;

    f32x4 acc[4][4] = {};

    for (int k0 = 0; k0 < K; k0 += TK) {
        gload16(X + (size_t)(m0 + srow) * K + k0 + skc,      &As[wid * 32][0]);
        gload16(X + (size_t)(m0 + srow + 16) * K + k0 + skc, &As[wid * 32 + 16][0]);
        gload16(W + (size_t)(n0 + srow) * K + k0 + skc,      &Bs[wid * 32][0]);
        gload16(W + (size_t)(n0 + srow + 16) * K + k0 + skc, &Bs[wid * 32 + 16][0]);
        __syncthreads();

        s16x8 a[4], b[4];
        #pragma unroll
        for (int m = 0; m < 4; ++m)
            a[m] = *(const s16x8*)&As[wm * 64 + m * 16 + (lane & 15)][(lane >> 4) * 8];
        #pragma unroll
        for (int n = 0; n < 4; ++n)
            b[n] = *(const s16x8*)&Bs[wn * 64 + n * 16 + (lane & 15)][(lane >> 4) * 8];
        #pragma unroll
        for (int m = 0; m < 4; ++m)
            #pragma unroll
            for (int n = 0; n < 4; ++n)
                acc[m][n] = __builtin_amdgcn_mfma_f32_16x16x32_bf16(a[m], b[n], acc[m][n], 0, 0, 0);
        __syncthreads();
    }

    #pragma unroll
    for (int m = 0; m < 4; ++m) {
        #pragma unroll
        for (int n = 0; n < 4; ++n) {
            int col = n0 + wn * 64 + n * 16 + (lane & 15);
            float badd = bias1[col] + (bias2 ? bias2[col] : 0.f);
            #pragma unroll
            for (int j = 0; j < 4; ++j) {
                int row = m0 + wm * 64 + m * 16 + (lane >> 4) * 4 + j;
                float v = acc[m][n][j] + badd + bf2f(CinBf[(size_t)row * G4 + col]);
                Cb[(size_t)row * G4 + col] = f2bf(v);
            }
        }
    }
}

// ---------------- preamble (R9/R6 layout) ----------------
#define P0 2048            // h0 (f4)
#define P1 (P0 + 1088)     // attn_w
#define P2 (P1 + 512)      // w_ih0
#define P3 (P2 + 4096)     // w_hh0
#define P4 (P3 + 4096)     // w_ih1
#define P5 (P4 + 4096)     // w_hh1
#define P6 (P5 + 576)      // comb_w transpose
#define P7 (P6 + 16)       // bias_f
#define P8 (P7 + 1024)     // build attn_in

__global__ __launch_bounds__(256) void preamble_kernel(
    const float* __restrict__ h0, const float* __restrict__ attn_w,
    const float* __restrict__ w_ih0, const float* __restrict__ w_hh0,
    const float* __restrict__ w_ih1, const float* __restrict__ w_hh1,
    const float* __restrict__ comb_w, const float* __restrict__ comb_b,
    const float* __restrict__ b_ih0, const float* __restrict__ b_hh0,
    const float* __restrict__ x, const int* __restrict__ x_emb,
    const float* __restrict__ c0,
    const float* __restrict__ e0, const float* __restrict__ e1,
    const float* __restrict__ e2, const float* __restrict__ e3,
    ushort* __restrict__ h0_bf, ushort* __restrict__ attn_w_bf,
    ushort* __restrict__ wih0_bf, ushort* __restrict__ whh0_bf,
    ushort* __restrict__ wih1_bf, ushort* __restrict__ whh1_bf,
    ushort* __restrict__ comb_wT, float* __restrict__ biasf,
    ushort* __restrict__ attn_in, ushort* __restrict__ xctx)
{
    const int bid = blockIdx.x;
    const int tid = threadIdx.x;

    if (bid < P5) {
        const float* s; ushort* d; int f;
        if (bid < P0)      { f = bid * 256 + tid;        s = h0;     d = h0_bf; }
        else if (bid < P1) { f = (bid - P0) * 256 + tid; s = attn_w; d = attn_w_bf; }
        else if (bid < P2) { f = (bid - P1) * 256 + tid; s = w_ih0;  d = wih0_bf; }
        else if (bid < P3) { f = (bid - P2) * 256 + tid; s = w_hh0;  d = whh0_bf; }
        else if (bid < P4) { f = (bid - P3) * 256 + tid; s = w_ih1;  d = wih1_bf; }
        else               { f = (bid - P4) * 256 + tid; s = w_hh1;  d = whh1_bf; }
        float4 v = ((const float4*)s)[f];
        ushort4 o = {f2bf(v.x), f2bf(v.y), f2bf(v.z), f2bf(v.w)};
        ((ushort4*)d)[f] = o;
    } else if (bid < P6) {
        int e = (bid - P5) * 256 + tid;
        int j = e >> 7, k = e & 127;
        comb_wT[e] = f2bf(comb_w[(size_t)k * XC + j]);
    } else if (bid < P7) {
        __shared__ float cb[IN];
        for (int i = tid; i < IN; i += 256) cb[i] = comb_b[i];
        __syncthreads();
        int i = (bid - P6) * 256 + tid;
        float s = b_ih0[i] + b_hh0[i];
        const float* row = w_ih0 + (size_t)i * IN;
        #pragma unroll 8
        for (int j = 0; j < IN; ++j) s += row[j] * cb[j];
        biasf[i] = s;
    } else {
        int b = bid - P7;
        int id0 = x_emb[b * 4 + 0];
        int id1 = x_emb[b * 4 + 1];
        int id2 = x_emb[b * 4 + 2];
        int id3 = x_emb[b * 4 + 3];
        ushort* dst = attn_in + (size_t)b * AK;
        for (int j = tid; j < AK; j += 256) {
            float v;
            if (j < 44)        v = x[b * NUM + j];
            else if (j < 108)  v = e0[id0 * 64 + (j - 44)];
            else if (j < 116)  v = e1[id1 * 8 + (j - 108)];
            else if (j < 124)  v = e2[id2 * 8 + (j - 116)];
            else if (j < 128)  v = e3[id3 * 4 + (j - 124)];
            else if (j < 1152) v = h0[b * H + (j - 128)];
            else               v = c0[b * H + (j - 1152)];
            unsigned short bf = f2bf(v);
            dst[j] = bf;
            if (j < IN) xctx[(size_t)b * XC + j] = bf;
        }
    }
}

// ---------------- softmax (merges split-K logits) -> aw_out ----------------
__global__ __launch_bounds__(256) void softmax_kernel(
    const float* __restrict__ logits_p, const float* __restrict__ attn_b,
    float* __restrict__ aw)
{
    int b = blockIdx.x;
    int tid = threadIdx.x;
    __shared__ float red[8];
    float v0 = attn_b[tid], v1 = attn_b[tid + 256];
    #pragma unroll
    for (int z = 0; z < 4; ++z) {
        const float* lp = logits_p + (size_t)z * B * T + (size_t)b * T;
        v0 += lp[tid];
        v1 += lp[tid + 256];
    }
    float m = fmaxf(v0, v1);
    #pragma unroll
    for (int off = 32; off > 0; off >>= 1) m = fmaxf(m, __shfl_down(m, off, 64));
    if ((tid & 63) == 0) red[tid >> 6] = m;
    __syncthreads();
    m = fmaxf(fmaxf(red[0], red[1]), fmaxf(red[2], red[3]));
    float e0 = expf(v0 - m), e1 = expf(v1 - m);
    float s = e0 + e1;
    #pragma unroll
    for (int off = 32; off > 0; off >>= 1) s += __shfl_down(s, off, 64);
    if ((tid & 63) == 0) red[4 + (tid >> 6)] = s;
    __syncthreads();
    s = red[4] + red[5] + red[6] + red[7];
    float inv = 1.0f / s;
    aw[(size_t)b * T + tid]       = e0 * inv;
    aw[(size_t)b * T + tid + 256] = e1 * inv;
}

// ---------------- ctx stream: t-split x2, lean, 16-deep ----------------
__global__ __launch_bounds__(256) void ctx_kernel(
    const float* __restrict__ enc, const float* __restrict__ aw,
    float* __restrict__ ctxp)
{
    const int b = blockIdx.x >> 1;
    const int z = blockIdx.x & 1;
    const int tid = threadIdx.x;
    __shared__ float w[256];
    w[tid] = aw[(size_t)b * T + z * 256 + tid];
    __syncthreads();

    const float* p = enc + (size_t)(z * 256) * BH + (size_t)b * H + tid * 4;
    float4 acc = {0.f, 0.f, 0.f, 0.f};
    for (int t0 = 0; t0 < 256; t0 += 16) {
        float4 vv[16];
        #pragma unroll
        for (int u = 0; u < 16; ++u)
            vv[u] = *(const float4*)(p + (size_t)(t0 + u) * BH);
        #pragma unroll
        for (int u = 0; u < 16; ++u) {
            float sw = w[t0 + u];
            acc.x += sw * vv[u].x; acc.y += sw * vv[u].y;
            acc.z += sw * vv[u].z; acc.w += sw * vv[u].w;
        }
    }
    *(float4*)(ctxp + (size_t)z * BH + (size_t)b * H + tid * 4) = acc;
}

// ---------------- ctx partial reduce (x2) -> xctx bf16 ----------------
__global__ __launch_bounds__(256) void ctx_reduce_kernel(
    const float* __restrict__ ctxp, ushort* __restrict__ xctx)
{
    int i = blockIdx.x * 256 + threadIdx.x;
    float4 a = ((const float4*)ctxp)[i];
    float4 c = ((const float4*)(ctxp + BH))[i];
    int f = i * 4;
    int b = f >> 10, h = f & 1023;
    ushort4 o = {f2bf(a.x + c.x), f2bf(a.y + c.y), f2bf(a.z + c.z), f2bf(a.w + c.w)};
    *(ushort4*)(xctx + (size_t)b * XC + IN + h) = o;
}

// ---------------- LSTM pointwise (vectorized x4, bf16 gates) ----------------
__global__ __launch_bounds__(256) void lstm_pointwise_kernel(
    const ushort* __restrict__ g, const float* __restrict__ c_in,
    float* __restrict__ h_out, float* __restrict__ c_out,
    ushort* __restrict__ h_bf)
{
    int q = blockIdx.x * 256 + threadIdx.x;   // 0 .. B*H/4-1
    int b = q >> 8;
    int j = (q & 255) * 4;
    const ushort* gr = g + (size_t)b * G4 + j;
    ushort4 gi4 = *(const ushort4*)(gr);
    ushort4 gf4 = *(const ushort4*)(gr + H);
    ushort4 gc4 = *(const ushort4*)(gr + 2 * H);
    ushort4 go4 = *(const ushort4*)(gr + 3 * H);
    size_t base = (size_t)b * H + j;
    float4 cin = *(const float4*)(c_in + base);
    float4 cv, hv;
    {
        float c0v = sigmf(bf2f(gf4.x)) * cin.x + sigmf(bf2f(gi4.x)) * tanhf(bf2f(gc4.x));
        float c1v = sigmf(bf2f(gf4.y)) * cin.y + sigmf(bf2f(gi4.y)) * tanhf(bf2f(gc4.y));
        float c2v = sigmf(bf2f(gf4.z)) * cin.z + sigmf(bf2f(gi4.z)) * tanhf(bf2f(gc4.z));
        float c3v = sigmf(bf2f(gf4.w)) * cin.w + sigmf(bf2f(gi4.w)) * tanhf(bf2f(gc4.w));
        cv = make_float4(c0v, c1v, c2v, c3v);
        hv = make_float4(sigmf(bf2f(go4.x)) * tanhf(c0v), sigmf(bf2f(go4.y)) * tanhf(c1v),
                         sigmf(bf2f(go4.z)) * tanhf(c2v), sigmf(bf2f(go4.w)) * tanhf(c3v));
    }
    *(float4*)(c_out + base) = cv;
    *(float4*)(h_out + base) = hv;
    if (h_bf) {
        ushort4 o = {f2bf(hv.x), f2bf(hv.y), f2bf(hv.z), f2bf(hv.w)};
        *(ushort4*)(h_bf + base) = o;
    }
}

// ---------------- pred ----------------
__global__ __launch_bounds__(256) void pred_kernel(
    const float* __restrict__ h2, const float* __restrict__ pw,
    const float* __restrict__ pb, float* __restrict__ out)
{
    int b = blockIdx.x;
    const float* row = h2 + (size_t)b * H;
    float s = 0.f;
    for (int j = threadIdx.x; j < H; j += 256) s += row[j] * pw[j];
    #pragma unroll
    for (int off = 32; off > 0; off >>= 1) s += __shfl_down(s, off, 64);
    __shared__ float sm[4];
    if ((threadIdx.x & 63) == 0) sm[threadIdx.x >> 6] = s;
    __syncthreads();
    if (threadIdx.x == 0) out[b] = sm[0] + sm[1] + sm[2] + sm[3] + pb[0];
}

extern "C" void kernel_launch(void* const* d_in, const int* in_sizes, int n_in,
                              void* d_out, int out_size, void* d_ws, size_t ws_size,
                              hipStream_t stream) {
    (void)in_sizes; (void)n_in; (void)out_size; (void)ws_size;
    const float* x      = (const float*)d_in[0];
    const int*   x_emb  = (const int*)d_in[1];
    const float* h0     = (const float*)d_in[2];
    const float* c0     = (const float*)d_in[3];
    const float* enc    = (const float*)d_in[4];
    const float* emb0   = (const float*)d_in[5];
    const float* emb1   = (const float*)d_in[6];
    const float* emb2   = (const float*)d_in[7];
    const float* emb3   = (const float*)d_in[8];
    const float* attn_w = (const float*)d_in[9];
    const float* attn_b = (const float*)d_in[10];
    const float* comb_w = (const float*)d_in[11];
    const float* comb_b = (const float*)d_in[12];
    const float* w_ih0  = (const float*)d_in[13];
    const float* w_hh0  = (const float*)d_in[14];
    const float* b_ih0  = (const float*)d_in[15];
    const float* b_hh0  = (const float*)d_in[16];
    const float* w_ih1  = (const float*)d_in[17];
    const float* w_hh1  = (const float*)d_in[18];
    const float* b_ih1  = (const float*)d_in[19];
    const float* b_hh1  = (const float*)d_in[20];
    const float* pred_w = (const float*)d_in[21];
    const float* pred_b = (const float*)d_in[22];

    float* out = (float*)d_out;
    float* h1_out = out + 1024;
    float* h2_out = out + 1024 + BH;
    float* c1_out = out + 1024 + 2 * BH;
    float* c2_out = out + 1024 + 3 * BH;
    float* aw_out = out + 1024 + 4 * BH;

    char* w = (char*)d_ws;
    ushort* attn_in_bf = (ushort*)w;  w += (size_t)B * AK * 2;
    ushort* h0_bf      = (ushort*)w;  w += (size_t)2 * BH * 2;
    ushort* attn_w_bf  = (ushort*)w;  w += (size_t)T * AK * 2;
    ushort* wih0_bf    = (ushort*)w;  w += (size_t)G4 * IN * 2;
    ushort* whh0_bf    = (ushort*)w;  w += (size_t)G4 * H * 2;
    ushort* wih1_bf    = (ushort*)w;  w += (size_t)G4 * H * 2;
    ushort* whh1_bf    = (ushort*)w;  w += (size_t)G4 * H * 2;
    ushort* comb_wT_bf = (ushort*)w;  w += (size_t)XC * IN * 2;
    ushort* W_f_bf     = (ushort*)w;  w += (size_t)G4 * XC * 2;
    float*  bias_f     = (float*)w;   w += (size_t)G4 * 4;
    ushort* xctx_bf    = (ushort*)w;  w += (size_t)B * XC * 2;
    ushort* h1_bf      = (ushort*)w;  w += (size_t)BH * 2;
    ushort* g1part     = (ushort*)w;  w += (size_t)B * G4 * 2;    // bf16 gates
    ushort* g2part     = (ushort*)w;  w += (size_t)B * G4 * 2;
    float*  logits_p   = (float*)w;   w += (size_t)4 * B * T * 4;
    float*  ctxp       = (float*)w;   w += (size_t)2 * BH * 4;
    // total ~70 MB

    preamble_kernel<<<P8, 256, 0, stream>>>(
        h0, attn_w, w_ih0, w_hh0, w_ih1, w_hh1, comb_w, comb_b, b_ih0, b_hh0,
        x, x_emb, c0, emb0, emb1, emb2, emb3,
        h0_bf, attn_w_bf, wih0_bf, whh0_bf, wih1_bf, whh1_bf, comb_wT_bf, bias_f,
        attn_in_bf, xctx_bf);

    // logits splitK + hh0 + hh1 + W_f : one launch, 928 blocks
    allgemms_kernel<<<928, 256, 0, stream>>>(
        attn_in_bf, attn_w_bf, logits_p,
        h0_bf, whh0_bf, whh1_bf, g1part, g2part,
        wih0_bf, comb_wT_bf, W_f_bf);

    softmax_kernel<<<B, 256, 0, stream>>>(logits_p, attn_b, aw_out);

    // enc stream, t-split x2, 16-deep
    ctx_kernel<<<2048, 256, 0, stream>>>(enc, aw_out, ctxp);

    ctx_reduce_kernel<<<(int)(BH / 4 / 256), 256, 0, stream>>>(ctxp, xctx_bf);

    // g1 = xctx @ W_f^T + g1part + bias_f -> bf16   (K=1152), 256 fat blocks
    gemm128_gates_kernel<<<dim3(G4 / TN, B / TM), 256, 0, stream>>>(
        xctx_bf, W_f_bf, bias_f, nullptr, g1part, g1part, XC);

    lstm_pointwise_kernel<<<(int)(BH / 4 / 256), 256, 0, stream>>>(g1part, c0, h1_out, c1_out, h1_bf);

    // g2 = h1 @ w_ih1^T + g2part + b_ih1 + b_hh1 -> bf16   (K=1024), 256 fat blocks
    gemm128_gates_kernel<<<dim3(G4 / TN, B / TM), 256, 0, stream>>>(
        h1_bf, wih1_bf, b_ih1, b_hh1, g2part, g2part, H);

    lstm_pointwise_kernel<<<(int)(BH / 4 / 256), 256, 0, stream>>>(g2part, c0 + BH, h2_out, c2_out, nullptr);

    pred_kernel<<<B, 256, 0, stream>>>(h2_out, pred_w, pred_b, out);
}

// Round 12
// 541.004 us; speedup vs baseline: 1.1439x; 1.0804x over previous
//
#include <hip/hip_runtime.h>
#include <hip/hip_bf16.h>

#define B 1024
#define H 1024
#define T 512
#define NUM 44
#define IN 128
#define AK (IN + 2 * H)   // 2176
#define XC (IN + H)       // 1152
#define G4 (4 * H)        // 4096
#define BH ((size_t)B * H)

typedef __attribute__((ext_vector_type(8))) short s16x8;
typedef __attribute__((ext_vector_type(4))) float f32x4;

__device__ __forceinline__ unsigned short f2bf(float f) {
    unsigned u = __float_as_uint(f);
    unsigned r = (u + 0x7fffu + ((u >> 16) & 1u)) >> 16;
    return (unsigned short)r;
}
__device__ __forceinline__ float bf2f(unsigned short u) {
    return __uint_as_float(((unsigned)u) << 16);
}
__device__ __forceinline__ float sigmf(float v) { return 1.0f / (1.0f + expf(-v)); }

__device__ __forceinline__ void gload16(const ushort* g, ushort* l) {
    __builtin_amdgcn_global_load_lds(
        (const __attribute__((address_space(1))) void*)g,
        (__attribute__((address_space(3))) void*)l,
        16, 0, 0);
}

#define TM 128
#define TN 128
#define TK 32

// ---------------- 128x128 GEMM core: C = X@W^T -> f32 and/or bf16 out ----------------
__device__ __forceinline__ void gemm_core(
    const ushort* __restrict__ X, const ushort* __restrict__ W,
    float* __restrict__ Cf, ushort* __restrict__ Cb,
    int kbeg, int kend, int ldx, int ldw, int ldc,
    int m0, int n0, ushort (*As)[TK], ushort (*Bs)[TK])
{
    const int tid = threadIdx.x;
    const int lane = tid & 63;
    const int wid = tid >> 6;
    const int wm = wid >> 1, wn = wid & 1;
    const int srow = wid * 32 + (lane >> 2);
    const int skc  = (lane & 3) * 8;

    f32x4 acc[4][4] = {};

    for (int k0 = kbeg; k0 < kend; k0 += TK) {
        gload16(X + (size_t)(m0 + srow) * ldx + k0 + skc,      &As[wid * 32][0]);
        gload16(X + (size_t)(m0 + srow + 16) * ldx + k0 + skc, &As[wid * 32 + 16][0]);
        gload16(W + (size_t)(n0 + srow) * ldw + k0 + skc,      &Bs[wid * 32][0]);
        gload16(W + (size_t)(n0 + srow + 16) * ldw + k0 + skc, &Bs[wid * 32 + 16][0]);
        __syncthreads();

        s16x8 a[4], b[4];
        #pragma unroll
        for (int m = 0; m < 4; ++m)
            a[m] = *(const s16x8*)&As[wm * 64 + m * 16 + (lane & 15)][(lane >> 4) * 8];
        #pragma unroll
        for (int n = 0; n < 4; ++n)
            b[n] = *(const s16x8*)&Bs[wn * 64 + n * 16 + (lane & 15)][(lane >> 4) * 8];
        #pragma unroll
        for (int m = 0; m < 4; ++m)
            #pragma unroll
            for (int n = 0; n < 4; ++n)
                acc[m][n] = __builtin_amdgcn_mfma_f32_16x16x32_bf16(a[m], b[n], acc[m][n], 0, 0, 0);
        __syncthreads();
    }

    #pragma unroll
    for (int m = 0; m < 4; ++m) {
        #pragma unroll
        for (int n = 0; n < 4; ++n) {
            int col = n0 + wn * 64 + n * 16 + (lane & 15);
            #pragma unroll
            for (int j = 0; j < 4; ++j) {
                int row = m0 + wm * 64 + m * 16 + (lane >> 4) * 4 + j;
                float v = acc[m][n][j];
                if (Cf) Cf[(size_t)row * ldc + col] = v;
                if (Cb) Cb[(size_t)row * ldc + col] = f2bf(v);
            }
        }
    }
}

// ---------------- ALL parallel GEMMs: logits splitK (128) + hh x2 (512) + W_f (288) ----------------
__global__ __launch_bounds__(256) void allgemms_kernel(
    const ushort* __restrict__ attn_in, const ushort* __restrict__ attn_w_bf,
    float* __restrict__ logits_p,
    const ushort* __restrict__ h0_bf,
    const ushort* __restrict__ whh0_bf, const ushort* __restrict__ whh1_bf,
    ushort* __restrict__ g1part, ushort* __restrict__ g2part,
    const ushort* __restrict__ wih0_bf, const ushort* __restrict__ comb_wT_bf,
    ushort* __restrict__ W_f_bf)
{
    __shared__ ushort As[TM][TK];
    __shared__ ushort Bs[TN][TK];
    const int rid = blockIdx.x;
    if (rid < 128) {
        int z = rid >> 5, t = rid & 31;
        int m0 = (t >> 2) * TM, n0 = (t & 3) * TN;
        gemm_core(attn_in, attn_w_bf, logits_p + (size_t)z * B * T, nullptr,
                  z * 544, z * 544 + 544, AK, AK, T, m0, n0, As, Bs);
    } else if (rid < 640) {
        int layer = (rid - 128) >> 8;
        int t = (rid - 128) & 255;
        int m0 = (t >> 5) * TM, n0 = (t & 31) * TN;
        gemm_core(h0_bf + (size_t)layer * BH, layer ? whh1_bf : whh0_bf,
                  nullptr, layer ? g2part : g1part,
                  0, H, H, H, G4, m0, n0, As, Bs);
    } else {
        int t = rid - 640;
        int m0 = (t / 9) * TM, n0 = (t % 9) * TN;
        gemm_core(wih0_bf, comb_wT_bf, nullptr, W_f_bf,
                  0, IN, IN, IN, XC, m0, n0, As, Bs);
    }
}

// ---------------- fat 128x128 tail GEMM: gates = X@W^T + bias(+bias2) + CinBf -> bf16 ----------------
__global__ __launch_bounds__(256) void gemm128_gates_kernel(
    const ushort* __restrict__ X, const ushort* __restrict__ W,
    const float* __restrict__ bias1, const float* __restrict__ bias2,
    const ushort* __restrict__ CinBf, ushort* __restrict__ Cb, int K)
{
    __shared__ ushort As[TM][TK];
    __shared__ ushort Bs[TN][TK];
    const int tid = threadIdx.x;
    const int lane = tid & 63;
    const int wid = tid >> 6;
    const int wm = wid >> 1, wn = wid & 1;
    const int m0 = blockIdx.y * TM;
    const int n0 = blockIdx.x * TN;
    const int srow = wid * 32 + (lane >> 2);
    const int skc  = (lane & 3) * 8;

    f32x4 acc[4][4] = {};

    for (int k0 = 0; k0 < K; k0 += TK) {
        gload16(X + (size_t)(m0 + srow) * K + k0 + skc,      &As[wid * 32][0]);
        gload16(X + (size_t)(m0 + srow + 16) * K + k0 + skc, &As[wid * 32 + 16][0]);
        gload16(W + (size_t)(n0 + srow) * K + k0 + skc,      &Bs[wid * 32][0]);
        gload16(W + (size_t)(n0 + srow + 16) * K + k0 + skc, &Bs[wid * 32 + 16][0]);
        __syncthreads();

        s16x8 a[4], b[4];
        #pragma unroll
        for (int m = 0; m < 4; ++m)
            a[m] = *(const s16x8*)&As[wm * 64 + m * 16 + (lane & 15)][(lane >> 4) * 8];
        #pragma unroll
        for (int n = 0; n < 4; ++n)
            b[n] = *(const s16x8*)&Bs[wn * 64 + n * 16 + (lane & 15)][(lane >> 4) * 8];
        #pragma unroll
        for (int m = 0; m < 4; ++m)
            #pragma unroll
            for (int n = 0; n < 4; ++n)
                acc[m][n] = __builtin_amdgcn_mfma_f32_16x16x32_bf16(a[m], b[n], acc[m][n], 0, 0, 0);
        __syncthreads();
    }

    #pragma unroll
    for (int m = 0; m < 4; ++m) {
        #pragma unroll
        for (int n = 0; n < 4; ++n) {
            int col = n0 + wn * 64 + n * 16 + (lane & 15);
            float badd = bias1[col] + (bias2 ? bias2[col] : 0.f);
            #pragma unroll
            for (int j = 0; j < 4; ++j) {
                int row = m0 + wm * 64 + m * 16 + (lane >> 4) * 4 + j;
                float v = acc[m][n][j] + badd + bf2f(CinBf[(size_t)row * G4 + col]);
                Cb[(size_t)row * G4 + col] = f2bf(v);
            }
        }
    }
}

// ---------------- preamble ----------------
#define P0 2048            // h0 (f4)
#define P1 (P0 + 1088)     // attn_w
#define P2 (P1 + 512)      // w_ih0
#define P3 (P2 + 4096)     // w_hh0
#define P4 (P3 + 4096)     // w_ih1
#define P5 (P4 + 4096)     // w_hh1
#define P6 (P5 + 576)      // comb_w transpose
#define P7 (P6 + 16)       // bias_f
#define P8 (P7 + 1024)     // build attn_in

__global__ __launch_bounds__(256) void preamble_kernel(
    const float* __restrict__ h0, const float* __restrict__ attn_w,
    const float* __restrict__ w_ih0, const float* __restrict__ w_hh0,
    const float* __restrict__ w_ih1, const float* __restrict__ w_hh1,
    const float* __restrict__ comb_w, const float* __restrict__ comb_b,
    const float* __restrict__ b_ih0, const float* __restrict__ b_hh0,
    const float* __restrict__ x, const int* __restrict__ x_emb,
    const float* __restrict__ c0,
    const float* __restrict__ e0, const float* __restrict__ e1,
    const float* __restrict__ e2, const float* __restrict__ e3,
    ushort* __restrict__ h0_bf, ushort* __restrict__ attn_w_bf,
    ushort* __restrict__ wih0_bf, ushort* __restrict__ whh0_bf,
    ushort* __restrict__ wih1_bf, ushort* __restrict__ whh1_bf,
    ushort* __restrict__ comb_wT, float* __restrict__ biasf,
    ushort* __restrict__ attn_in, ushort* __restrict__ xctx)
{
    const int bid = blockIdx.x;
    const int tid = threadIdx.x;

    if (bid < P5) {
        const float* s; ushort* d; int f;
        if (bid < P0)      { f = bid * 256 + tid;        s = h0;     d = h0_bf; }
        else if (bid < P1) { f = (bid - P0) * 256 + tid; s = attn_w; d = attn_w_bf; }
        else if (bid < P2) { f = (bid - P1) * 256 + tid; s = w_ih0;  d = wih0_bf; }
        else if (bid < P3) { f = (bid - P2) * 256 + tid; s = w_hh0;  d = whh0_bf; }
        else if (bid < P4) { f = (bid - P3) * 256 + tid; s = w_ih1;  d = wih1_bf; }
        else               { f = (bid - P4) * 256 + tid; s = w_hh1;  d = whh1_bf; }
        float4 v = ((const float4*)s)[f];
        ushort4 o = {f2bf(v.x), f2bf(v.y), f2bf(v.z), f2bf(v.w)};
        ((ushort4*)d)[f] = o;
    } else if (bid < P6) {
        int e = (bid - P5) * 256 + tid;
        int j = e >> 7, k = e & 127;
        comb_wT[e] = f2bf(comb_w[(size_t)k * XC + j]);
    } else if (bid < P7) {
        __shared__ float cb[IN];
        for (int i = tid; i < IN; i += 256) cb[i] = comb_b[i];
        __syncthreads();
        int i = (bid - P6) * 256 + tid;
        float s = b_ih0[i] + b_hh0[i];
        const float* row = w_ih0 + (size_t)i * IN;
        #pragma unroll 8
        for (int j = 0; j < IN; ++j) s += row[j] * cb[j];
        biasf[i] = s;
    } else {
        int b = bid - P7;
        int id0 = x_emb[b * 4 + 0];
        int id1 = x_emb[b * 4 + 1];
        int id2 = x_emb[b * 4 + 2];
        int id3 = x_emb[b * 4 + 3];
        ushort* dst = attn_in + (size_t)b * AK;
        for (int j = tid; j < AK; j += 256) {
            float v;
            if (j < 44)        v = x[b * NUM + j];
            else if (j < 108)  v = e0[id0 * 64 + (j - 44)];
            else if (j < 116)  v = e1[id1 * 8 + (j - 108)];
            else if (j < 124)  v = e2[id2 * 8 + (j - 116)];
            else if (j < 128)  v = e3[id3 * 4 + (j - 124)];
            else if (j < 1152) v = h0[b * H + (j - 128)];
            else               v = c0[b * H + (j - 1152)];
            unsigned short bf = f2bf(v);
            dst[j] = bf;
            if (j < IN) xctx[(size_t)b * XC + j] = bf;
        }
    }
}

// ---------------- softmax (merges split-K logits) -> aw_out ----------------
__global__ __launch_bounds__(256) void softmax_kernel(
    const float* __restrict__ logits_p, const float* __restrict__ attn_b,
    float* __restrict__ aw)
{
    int b = blockIdx.x;
    int tid = threadIdx.x;
    __shared__ float red[8];
    float v0 = attn_b[tid], v1 = attn_b[tid + 256];
    #pragma unroll
    for (int z = 0; z < 4; ++z) {
        const float* lp = logits_p + (size_t)z * B * T + (size_t)b * T;
        v0 += lp[tid];
        v1 += lp[tid + 256];
    }
    float m = fmaxf(v0, v1);
    #pragma unroll
    for (int off = 32; off > 0; off >>= 1) m = fmaxf(m, __shfl_down(m, off, 64));
    if ((tid & 63) == 0) red[tid >> 6] = m;
    __syncthreads();
    m = fmaxf(fmaxf(red[0], red[1]), fmaxf(red[2], red[3]));
    float e0 = expf(v0 - m), e1 = expf(v1 - m);
    float s = e0 + e1;
    #pragma unroll
    for (int off = 32; off > 0; off >>= 1) s += __shfl_down(s, off, 64);
    if ((tid & 63) == 0) red[4 + (tid >> 6)] = s;
    __syncthreads();
    s = red[4] + red[5] + red[6] + red[7];
    float inv = 1.0f / s;
    aw[(size_t)b * T + tid]       = e0 * inv;
    aw[(size_t)b * T + tid + 256] = e1 * inv;
}

// ---------------- ctx stream: 4 rows/block (wave=row), t-split x4, contiguous 16KB/block/t ----------------
// bid -> bg = bid>>2 (4 consecutive b's), z = bid&3 (128 t's). Wave w owns row b = bg*4+w:
// per t reads enc[t][b][0..1024) as 4 x 1KB back-to-back wave-loads. Block's 4 rows adjacent
// -> 16KB contiguous per t-step.
__global__ __launch_bounds__(256) void ctx_kernel(
    const float* __restrict__ enc, const float* __restrict__ aw,
    float* __restrict__ ctxp)
{
    const int bg = blockIdx.x >> 2;
    const int z  = blockIdx.x & 3;
    const int w  = threadIdx.x >> 6;
    const int lane = threadIdx.x & 63;
    const int b = bg * 4 + w;

    __shared__ float wts[4][128];
    wts[w][lane]      = aw[(size_t)b * T + z * 128 + lane];
    wts[w][lane + 64] = aw[(size_t)b * T + z * 128 + 64 + lane];
    __syncthreads();

    const float* p = enc + (size_t)(z * 128) * BH + (size_t)b * H + lane * 4;
    float4 acc[4] = {};
    for (int t0 = 0; t0 < 128; t0 += 4) {
        float4 v[4][4];
        #pragma unroll
        for (int u = 0; u < 4; ++u)
            #pragma unroll
            for (int q = 0; q < 4; ++q)
                v[u][q] = *(const float4*)(p + (size_t)(t0 + u) * BH + q * 256);
        #pragma unroll
        for (int u = 0; u < 4; ++u) {
            float sw = wts[w][t0 + u];
            #pragma unroll
            for (int q = 0; q < 4; ++q) {
                acc[q].x += sw * v[u][q].x; acc[q].y += sw * v[u][q].y;
                acc[q].z += sw * v[u][q].z; acc[q].w += sw * v[u][q].w;
            }
        }
    }
    float* o = ctxp + (size_t)z * BH + (size_t)b * H + lane * 4;
    #pragma unroll
    for (int q = 0; q < 4; ++q)
        *(float4*)(o + q * 256) = acc[q];
}

// ---------------- ctx partial reduce (x4) -> xctx bf16 ----------------
__global__ __launch_bounds__(256) void ctx_reduce_kernel(
    const float* __restrict__ ctxp, ushort* __restrict__ xctx)
{
    int i = blockIdx.x * 256 + threadIdx.x;
    float4 a  = ((const float4*)ctxp)[i];
    float4 b4 = ((const float4*)(ctxp + BH))[i];
    float4 c  = ((const float4*)(ctxp + 2 * BH))[i];
    float4 d  = ((const float4*)(ctxp + 3 * BH))[i];
    int f = i * 4;
    int b = f >> 10, h = f & 1023;
    ushort4 o = {f2bf(a.x + b4.x + c.x + d.x), f2bf(a.y + b4.y + c.y + d.y),
                 f2bf(a.z + b4.z + c.z + d.z), f2bf(a.w + b4.w + c.w + d.w)};
    *(ushort4*)(xctx + (size_t)b * XC + IN + h) = o;
}

// ---------------- LSTM pointwise (vectorized x4, bf16 gates) ----------------
__global__ __launch_bounds__(256) void lstm_pointwise_kernel(
    const ushort* __restrict__ g, const float* __restrict__ c_in,
    float* __restrict__ h_out, float* __restrict__ c_out,
    ushort* __restrict__ h_bf)
{
    int q = blockIdx.x * 256 + threadIdx.x;   // 0 .. B*H/4-1
    int b = q >> 8;
    int j = (q & 255) * 4;
    const ushort* gr = g + (size_t)b * G4 + j;
    ushort4 gi4 = *(const ushort4*)(gr);
    ushort4 gf4 = *(const ushort4*)(gr + H);
    ushort4 gc4 = *(const ushort4*)(gr + 2 * H);
    ushort4 go4 = *(const ushort4*)(gr + 3 * H);
    size_t base = (size_t)b * H + j;
    float4 cin = *(const float4*)(c_in + base);
    float4 cv, hv;
    {
        float c0v = sigmf(bf2f(gf4.x)) * cin.x + sigmf(bf2f(gi4.x)) * tanhf(bf2f(gc4.x));
        float c1v = sigmf(bf2f(gf4.y)) * cin.y + sigmf(bf2f(gi4.y)) * tanhf(bf2f(gc4.y));
        float c2v = sigmf(bf2f(gf4.z)) * cin.z + sigmf(bf2f(gi4.z)) * tanhf(bf2f(gc4.z));
        float c3v = sigmf(bf2f(gf4.w)) * cin.w + sigmf(bf2f(gi4.w)) * tanhf(bf2f(gc4.w));
        cv = make_float4(c0v, c1v, c2v, c3v);
        hv = make_float4(sigmf(bf2f(go4.x)) * tanhf(c0v), sigmf(bf2f(go4.y)) * tanhf(c1v),
                         sigmf(bf2f(go4.z)) * tanhf(c2v), sigmf(bf2f(go4.w)) * tanhf(c3v));
    }
    *(float4*)(c_out + base) = cv;
    *(float4*)(h_out + base) = hv;
    if (h_bf) {
        ushort4 o = {f2bf(hv.x), f2bf(hv.y), f2bf(hv.z), f2bf(hv.w)};
        *(ushort4*)(h_bf + base) = o;
    }
}

// ---------------- pred ----------------
__global__ __launch_bounds__(256) void pred_kernel(
    const float* __restrict__ h2, const float* __restrict__ pw,
    const float* __restrict__ pb, float* __restrict__ out)
{
    int b = blockIdx.x;
    const float* row = h2 + (size_t)b * H;
    float s = 0.f;
    for (int j = threadIdx.x; j < H; j += 256) s += row[j] * pw[j];
    #pragma unroll
    for (int off = 32; off > 0; off >>= 1) s += __shfl_down(s, off, 64);
    __shared__ float sm[4];
    if ((threadIdx.x & 63) == 0) sm[threadIdx.x >> 6] = s;
    __syncthreads();
    if (threadIdx.x == 0) out[b] = sm[0] + sm[1] + sm[2] + sm[3] + pb[0];
}

extern "C" void kernel_launch(void* const* d_in, const int* in_sizes, int n_in,
                              void* d_out, int out_size, void* d_ws, size_t ws_size,
                              hipStream_t stream) {
    (void)in_sizes; (void)n_in; (void)out_size; (void)ws_size;
    const float* x      = (const float*)d_in[0];
    const int*   x_emb  = (const int*)d_in[1];
    const float* h0     = (const float*)d_in[2];
    const float* c0     = (const float*)d_in[3];
    const float* enc    = (const float*)d_in[4];
    const float* emb0   = (const float*)d_in[5];
    const float* emb1   = (const float*)d_in[6];
    const float* emb2   = (const float*)d_in[7];
    const float* emb3   = (const float*)d_in[8];
    const float* attn_w = (const float*)d_in[9];
    const float* attn_b = (const float*)d_in[10];
    const float* comb_w = (const float*)d_in[11];
    const float* comb_b = (const float*)d_in[12];
    const float* w_ih0  = (const float*)d_in[13];
    const float* w_hh0  = (const float*)d_in[14];
    const float* b_ih0  = (const float*)d_in[15];
    const float* b_hh0  = (const float*)d_in[16];
    const float* w_ih1  = (const float*)d_in[17];
    const float* w_hh1  = (const float*)d_in[18];
    const float* b_ih1  = (const float*)d_in[19];
    const float* b_hh1  = (const float*)d_in[20];
    const float* pred_w = (const float*)d_in[21];
    const float* pred_b = (const float*)d_in[22];

    float* out = (float*)d_out;
    float* h1_out = out + 1024;
    float* h2_out = out + 1024 + BH;
    float* c1_out = out + 1024 + 2 * BH;
    float* c2_out = out + 1024 + 3 * BH;
    float* aw_out = out + 1024 + 4 * BH;

    char* w = (char*)d_ws;
    ushort* attn_in_bf = (ushort*)w;  w += (size_t)B * AK * 2;
    ushort* h0_bf      = (ushort*)w;  w += (size_t)2 * BH * 2;
    ushort* attn_w_bf  = (ushort*)w;  w += (size_t)T * AK * 2;
    ushort* wih0_bf    = (ushort*)w;  w += (size_t)G4 * IN * 2;
    ushort* whh0_bf    = (ushort*)w;  w += (size_t)G4 * H * 2;
    ushort* wih1_bf    = (ushort*)w;  w += (size_t)G4 * H * 2;
    ushort* whh1_bf    = (ushort*)w;  w += (size_t)G4 * H * 2;
    ushort* comb_wT_bf = (ushort*)w;  w += (size_t)XC * IN * 2;
    ushort* W_f_bf     = (ushort*)w;  w += (size_t)G4 * XC * 2;
    float*  bias_f     = (float*)w;   w += (size_t)G4 * 4;
    ushort* xctx_bf    = (ushort*)w;  w += (size_t)B * XC * 2;
    ushort* h1_bf      = (ushort*)w;  w += (size_t)BH * 2;
    ushort* g1part     = (ushort*)w;  w += (size_t)B * G4 * 2;    // bf16 gates
    ushort* g2part     = (ushort*)w;  w += (size_t)B * G4 * 2;
    float*  logits_p   = (float*)w;   w += (size_t)4 * B * T * 4;
    float*  ctxp       = (float*)w;   w += (size_t)4 * BH * 4;
    // total ~78 MB

    preamble_kernel<<<P8, 256, 0, stream>>>(
        h0, attn_w, w_ih0, w_hh0, w_ih1, w_hh1, comb_w, comb_b, b_ih0, b_hh0,
        x, x_emb, c0, emb0, emb1, emb2, emb3,
        h0_bf, attn_w_bf, wih0_bf, whh0_bf, wih1_bf, whh1_bf, comb_wT_bf, bias_f,
        attn_in_bf, xctx_bf);

    // logits splitK + hh0 + hh1 + W_f : one launch, 928 blocks
    allgemms_kernel<<<928, 256, 0, stream>>>(
        attn_in_bf, attn_w_bf, logits_p,
        h0_bf, whh0_bf, whh1_bf, g1part, g2part,
        wih0_bf, comb_wT_bf, W_f_bf);

    softmax_kernel<<<B, 256, 0, stream>>>(logits_p, attn_b, aw_out);

    // enc stream: 4 rows/block, z-split x4, 1024 blocks
    ctx_kernel<<<1024, 256, 0, stream>>>(enc, aw_out, ctxp);

    ctx_reduce_kernel<<<(int)(BH / 4 / 256), 256, 0, stream>>>(ctxp, xctx_bf);

    // g1 = xctx @ W_f^T + g1part + bias_f -> bf16   (K=1152), 256 fat blocks
    gemm128_gates_kernel<<<dim3(G4 / TN, B / TM), 256, 0, stream>>>(
        xctx_bf, W_f_bf, bias_f, nullptr, g1part, g1part, XC);

    lstm_pointwise_kernel<<<(int)(BH / 4 / 256), 256, 0, stream>>>(g1part, c0, h1_out, c1_out, h1_bf);

    // g2 = h1 @ w_ih1^T + g2part + b_ih1 + b_hh1 -> bf16   (K=1024), 256 fat blocks
    gemm128_gates_kernel<<<dim3(G4 / TN, B / TM), 256, 0, stream>>>(
        h1_bf, wih1_bf, b_ih1, b_hh1, g2part, g2part, H);

    lstm_pointwise_kernel<<<(int)(BH / 4 / 256), 256, 0, stream>>>(g2part, c0 + BH, h2_out, c2_out, nullptr);

    pred_kernel<<<B, 256, 0, stream>>>(h2_out, pred_w, pred_b, out);
}